// Round 2
// baseline (118.259 us; speedup 1.0000x reference)
//
#include <hip/hip_runtime.h>

// SIR recurrence: 2047 strictly-sequential steps of a 4-state quadratic map.
// R2: move the 4 global stores/step out of the serial loop (they caused
// ~40 of 53 cyc/step — store drain and/or single-wave issue cadence).
// Lane 0 computes the recurrence and does ONE ds_write_b128 per step;
// all 256 threads then expand LDS rows {u,s1,v,s3} -> out rows
// {u,s1,v,s3,0} in a parallel writeback.
//
// FP op order is FROZEN from R1 (absmax was exactly 0.0):
//   t  = u*v
//   c  = fmaf(gamma, t, delta)     gamma = w3*w3/1000, delta = fmaf(w3,b3,b3)
//   nu = fmaf(L, u, c)             L = 1 - w2sq - w4sq
//   nv = v - c
//   s1 = fmaf(w2sq, u, s1)
//   s3 = fmaf(w4sq, u, s3)

__global__ __launch_bounds__(256) void sir_kernel(
    const float* __restrict__ x, const float* __restrict__ w2p,
    const float* __restrict__ w3p, const float* __restrict__ b3p,
    const float* __restrict__ w4p, const int* __restrict__ np,
    float* __restrict__ out) {
  __shared__ __align__(16) float buf[2048 * 4];  // row i: {u, s1, v, s3}
  const int n = *np;
  const int rows = n - 1;  // 2047
  const int tid = threadIdx.x;

  if (tid == 0) {
    const float w2 = *w2p, w3 = *w3p, b3 = *b3p, w4 = *w4p;
    const float w2sq  = w2 * w2;
    const float w4sq  = w4 * w4;
    const float L     = 1.0f - w2sq - w4sq;
    const float gamma = (w3 * w3) / 1000.0f;
    const float delta = fmaf(w3, b3, b3);

    float u  = x[0];
    float s1 = x[1];
    float v  = x[2];
    float s3 = x[3];

    float4* __restrict__ q = (float4*)buf;
#pragma unroll 8
    for (int i = 0; i < rows; ++i) {
      const float t  = u * v;
      const float c  = fmaf(gamma, t, delta);
      const float nu = fmaf(L, u, c);
      const float nv = v - c;
      s1 = fmaf(w2sq, u, s1);
      s3 = fmaf(w4sq, u, s3);
      u = nu;
      v = nv;
      q[i] = make_float4(nu, s1, nv, s3);  // one ds_write_b128 per step
    }
  }
  __syncthreads();  // other 255 threads sleep here (no issue slots consumed)

  // Parallel writeback: out[5r + {0..3}] = buf[4r + {0..3}], out[5r+4] = 0.
  // (d_out is re-poisoned to 0xAA before every launch, so col 4 must be
  // written every call.)
  const float4* __restrict__ q = (const float4*)buf;
  for (int r = tid; r < rows; r += 256) {
    const float4 w = q[r];
    float* __restrict__ o = out + 5 * r;
    o[0] = w.x;
    o[1] = w.y;
    o[2] = w.z;
    o[3] = w.w;
    o[4] = 0.0f;
  }
}

extern "C" void kernel_launch(void* const* d_in, const int* in_sizes, int n_in,
                              void* d_out, int out_size, void* d_ws, size_t ws_size,
                              hipStream_t stream) {
  const float* x   = (const float*)d_in[0];
  const float* w2  = (const float*)d_in[1];
  const float* w3  = (const float*)d_in[2];
  const float* b3  = (const float*)d_in[3];
  const float* w4  = (const float*)d_in[4];
  const int*   n   = (const int*)d_in[5];
  float* out = (float*)d_out;
  sir_kernel<<<1, 256, 0, stream>>>(x, w2, w3, b3, w4, n, out);
}